// Round 2
// baseline (339.241 us; speedup 1.0000x reference)
//
#include <hip/hip_runtime.h>
#include <stdint.h>

typedef short bf16x8 __attribute__((ext_vector_type(8)));
typedef unsigned short u16x8 __attribute__((ext_vector_type(8)));
typedef float f32x4 __attribute__((ext_vector_type(4)));
typedef float f32x8 __attribute__((ext_vector_type(8)));

constexpr int BT_TOT = 768;   // B*T
constexpr int M_N    = 512;   // nodes (and contraction length)
constexpr int DD     = 64;    // Din = Dout
constexpr int BMM    = 32;    // m per workgroup
constexpr int BBB    = 8;     // bt per workgroup
constexpr int KC     = 128;   // x chunk (n per stage)
constexpr int XROW   = 136;   // xT row stride (elems): 272B = 16B-aligned, bank step 4
constexpr int WROW   = 72;    // W' row stride (elems): 144B = 16B-aligned, bank step 4

__device__ __forceinline__ unsigned short f2bf(float f) {
  unsigned u = __builtin_bit_cast(unsigned, f);
  u += 0x7fffu + ((u >> 16) & 1u);          // RNE
  return (unsigned short)(u >> 16);
}

// out[bt][m][l] = sum_d ( sum_n adj[m][n]*x[bt][n][d] ) * W[m][d][l] + bias[m][l]
// All globals are FLOAT32; internal compute bf16 MFMA with f32 accumulate.
__global__ __launch_bounds__(256, 2)
void lineagc_fused(const float* __restrict__ xg,    // [768][512][64] f32
                   const float* __restrict__ adjg,  // [512][512] f32
                   const float* __restrict__ wgt,   // [512][64][64] f32
                   const float* __restrict__ bias,  // [512][64] f32 (route_bias[m][0][l])
                   float* __restrict__ outg)        // [768][512][64] f32
{
  // LDS: xT (double-buffered transposed x chunk) 34816B, aliased by W' in stage 2.
  //      Hb: per-WG intermediate H, bf16, swizzled. 32768B.  Total 67584B -> 2 WG/CU.
  __shared__ unsigned short xT[2][64 * XROW];
  __shared__ unsigned short Hb[BBB * BMM * DD];

  const int tid   = threadIdx.x;
  const int lane  = tid & 63;
  const int wv    = tid >> 6;       // wave 0..3
  const int l15   = lane & 15;
  const int gg    = lane >> 4;      // k-group 0..3
  const int mblk  = blockIdx.x * BMM;
  const int btblk = blockIdx.y * BBB;

  const int mt = wv & 1;            // m-tile (16 rows) owned by this wave
  const int dh = wv >> 1;           // d-half: d-tiles {2*dh, 2*dh+1}

  // ---- preload A-fragments (adj rows are n-contiguous -> natural k-runs) ----
  bf16x8 afr[16];
  {
    const float* ap = adjg + (size_t)(mblk + mt*16 + l15) * M_N + gg*8;
    #pragma unroll
    for (int ks = 0; ks < 16; ++ks) {
      f32x8 a = *(const f32x8*)(ap + ks*32);
      u16x8 r;
      #pragma unroll
      for (int i = 0; i < 8; ++i) r[i] = f2bf(a[i]);
      afr[ks] = __builtin_bit_cast(bf16x8, r);
    }
  }

  // x staging decomposition: thread = (nq = n-quad, doct = d-oct). nq fastest so
  // the transposed ds_write_b64 sweep is bank-conflict-free.
  const int nq   = tid & 31;
  const int doct = tid >> 5;
  const float* xb_base = xg + (size_t)btblk * (M_N * DD);

  f32x8 x0, x1, x2, x3;

  #pragma unroll 1
  for (int b = 0; b < BBB; ++b) {
    const float* xb = xb_base + (size_t)b * (M_N * DD);
    f32x4 acc0 = {0.f,0.f,0.f,0.f};
    f32x4 acc1 = {0.f,0.f,0.f,0.f};

    { const float* p = xb + (0*KC + nq*4)*DD + doct*8;
      x0 = *(const f32x8*)p;        x1 = *(const f32x8*)(p+DD);
      x2 = *(const f32x8*)(p+2*DD); x3 = *(const f32x8*)(p+3*DD); }

    #pragma unroll
    for (int c = 0; c < 4; ++c) {
      unsigned short* xt = &xT[c & 1][0];
      // transpose-write chunk c (cvt f32->bf16): xT[d][n] = bf16(x[b][c*KC+n][d])
      #pragma unroll
      for (int e = 0; e < 8; ++e) {
        int d = doct*8 + e;
        unsigned v0 = (unsigned)f2bf(x0[e]) | ((unsigned)f2bf(x1[e]) << 16);
        unsigned v1 = (unsigned)f2bf(x2[e]) | ((unsigned)f2bf(x3[e]) << 16);
        uint2 vv; vv.x = v0; vv.y = v1;
        *(uint2*)(xt + d*XROW + nq*4) = vv;     // ds_write_b64
      }
      if (c < 3) {  // issue next chunk's global loads early (hide HBM latency)
        const float* p = xb + ((c+1)*KC + nq*4)*DD + doct*8;
        x0 = *(const f32x8*)p;        x1 = *(const f32x8*)(p+DD);
        x2 = *(const f32x8*)(p+2*DD); x3 = *(const f32x8*)(p+3*DD);
      }
      __syncthreads();   // single barrier/chunk: next write goes to the other buffer
      #pragma unroll
      for (int kl = 0; kl < 4; ++kl) {
        int n0 = kl*32 + gg*8;
        const unsigned short* b0p = xt + ((dh*2+0)*16 + l15)*XROW + n0;
        const unsigned short* b1p = xt + ((dh*2+1)*16 + l15)*XROW + n0;
        bf16x8 bf0 = __builtin_bit_cast(bf16x8, *(const u16x8*)b0p);
        bf16x8 bf1 = __builtin_bit_cast(bf16x8, *(const u16x8*)b1p);
        acc0 = __builtin_amdgcn_mfma_f32_16x16x32_bf16(afr[c*4+kl], bf0, acc0, 0,0,0);
        acc1 = __builtin_amdgcn_mfma_f32_16x16x32_bf16(afr[c*4+kl], bf1, acc1, 0,0,0);
      }
    }

    // write H[b][m][d] (bf16, XOR-swizzled so stage-2 b-indexed reads spread banks)
    #pragma unroll
    for (int dt = 0; dt < 2; ++dt) {
      int d = (dh*2 + dt)*16 + l15;
      #pragma unroll
      for (int r = 0; r < 4; ++r) {
        int m = mt*16 + gg*4 + r;               // D row = (lane>>4)*4 + reg
        unsigned byte = (unsigned)(b*4096 + m*128 + d*2);
        byte ^= ((unsigned)((b & 7) ^ (m & 7)) << 4);
        float v = dt ? acc1[r] : acc0[r];
        *(unsigned short*)((char*)Hb + byte) = f2bf(v);
      }
    }
  }
  __syncthreads();

  // ---- stage 2: out[b'][m][l] = sum_d H[b'][m][d] * W[m][d][l] + bias ----
  unsigned short* wb = &xT[0][0];   // W' buffer: [2 m][64 l][WROW], aliases xT
  const int dp = tid & 31;          // d-pair
  const int lo = tid >> 5;          // l-oct

  f32x8 w0, w1, w2, w3;
  { const float* q = wgt + ((size_t)mblk*64 + dp*2)*64 + lo*8;
    w0 = *(const f32x8*)q;         w1 = *(const f32x8*)(q+64);
    w2 = *(const f32x8*)(q+4096);  w3 = *(const f32x8*)(q+4096+64); }

  #pragma unroll 1
  for (int p = 0; p < 16; ++p) {
    // transpose-write W' for m = {2p, 2p+1}: W'[l][d] = bf16(W[m][d][l])
    #pragma unroll
    for (int e = 0; e < 8; ++e) {
      int lrow = lo*8 + e;
      unsigned v0 = (unsigned)f2bf(w0[e]) | ((unsigned)f2bf(w1[e]) << 16);
      unsigned v1 = (unsigned)f2bf(w2[e]) | ((unsigned)f2bf(w3[e]) << 16);
      *(unsigned*)(wb + lrow*WROW + dp*2) = v0;
      *(unsigned*)(wb + (64 + lrow)*WROW + dp*2) = v1;
    }
    if (p < 15) {
      const float* q = wgt + ((size_t)(mblk + (p+1)*2)*64 + dp*2)*64 + lo*8;
      w0 = *(const f32x8*)q;         w1 = *(const f32x8*)(q+64);
      w2 = *(const f32x8*)(q+4096);  w3 = *(const f32x8*)(q+4096+64);
    }
    __syncthreads();
    #pragma unroll
    for (int mm = 0; mm < 2; ++mm) {
      int m = p*2 + mm;
      f32x4 acc = {0.f,0.f,0.f,0.f};
      #pragma unroll
      for (int ks = 0; ks < 2; ++ks) {
        int d0 = ks*32 + gg*8;
        unsigned byte = (unsigned)((l15 & 7)*4096 + m*128 + d0*2);
        byte ^= ((unsigned)(((l15 & 7) ^ (m & 7))) << 4);
        bf16x8 af = __builtin_bit_cast(bf16x8, *(const u16x8*)((char*)Hb + byte));
        bf16x8 bfw = __builtin_bit_cast(bf16x8,
            *(const u16x8*)(wb + (mm*64 + wv*16 + l15)*WROW + d0));
        acc = __builtin_amdgcn_mfma_f32_16x16x32_bf16(af, bfw, acc, 0,0,0);
      }
      if (gg < 2) {                       // D rows 0..7 are the valid bt rows
        int lout = wv*16 + l15;
        float bv = bias[(mblk + m)*64 + lout];
        size_t obase = ((size_t)btblk*M_N + (mblk + m))*DD + lout;
        #pragma unroll
        for (int r = 0; r < 4; ++r) {
          int bt_off = gg*4 + r;
          outg[obase + (size_t)bt_off * (M_N*DD)] = acc[r] + bv;
        }
      }
    }
    __syncthreads();  // wb is single-buffered per pair
  }
}

extern "C" void kernel_launch(void* const* d_in, const int* in_sizes, int n_in,
                              void* d_out, int out_size, void* d_ws, size_t ws_size,
                              hipStream_t stream) {
  const float* xg   = (const float*)d_in[0];
  const float* adjg = (const float*)d_in[1];
  const float* wgt  = (const float*)d_in[2];
  const float* bg   = (const float*)d_in[3];
  float* outg = (float*)d_out;
  dim3 grid(M_N / BMM, BT_TOT / BBB);   // (16, 96) = 1536 workgroups
  lineagc_fused<<<grid, dim3(256), 0, stream>>>(xg, adjg, wgt, bg, outg);
}

// Round 3
// 170.377 us; speedup vs baseline: 1.9911x; 1.9911x over previous
//
#include <hip/hip_runtime.h>
#include <stdint.h>

typedef short bf16x8 __attribute__((ext_vector_type(8)));
typedef unsigned short u16x8 __attribute__((ext_vector_type(8)));
typedef float f32x4 __attribute__((ext_vector_type(4)));
typedef float f32x8 __attribute__((ext_vector_type(8)));

constexpr int BT_TOT = 768;   // B*T
constexpr int M_N    = 512;   // nodes (contraction length for stage 1)
constexpr int DD     = 64;    // Din = Dout
constexpr int KC     = 128;   // x chunk (n per stage-1 phase)
constexpr int XROW   = 136;   // xT row stride (elems): 272B, 16B-aligned, bank step 4
constexpr int WROW   = 72;    // W' row stride (elems): 144B, 16B-aligned, bank step 4

__device__ __forceinline__ unsigned short f2bf(float f) {
  unsigned u = __builtin_bit_cast(unsigned, f);
  u += 0x7fffu + ((u >> 16) & 1u);          // RNE
  return (unsigned short)(u >> 16);
}

// ---------------- Kernel A ----------------
// H[bt][m][d] = sum_n adj[m][n] * x[bt][n][d]   (bf16 result)
// Stored into the FIRST 128 bytes of each 256-byte d_out row (row = bt*512+m).
// Kernel B later overwrites each full row with f32 out; row ownership is exact,
// so d_out doubles as the H workspace with no races and no d_ws use.
__global__ __launch_bounds__(256, 3)
void gconv_h(const float* __restrict__ xg,    // [768][512][64] f32
             const float* __restrict__ adjg,  // [512][512] f32
             char* __restrict__ hout)         // d_out viewed as bytes
{
  __shared__ unsigned short xT[2][64 * XROW];   // 34816 B -> 3 WG/CU

  const int bt    = blockIdx.x;        // x-fastest: one bt's 4 m-blocks are 768 apart
  const int mbase = blockIdx.y * 128;  //   -> same XCD residue, x served from L2/L3
  const int tid   = threadIdx.x;
  const int lane  = tid & 63;
  const int wv    = tid >> 6;          // wave 0..3
  const int l15   = lane & 15;
  const int gg    = lane >> 4;         // k-group 0..3
  const int nq    = tid & 31;          // n-quad for staging
  const int doct  = tid >> 5;          // d-oct for staging (uniform per wave-half)

  const int mrow0 = mbase + wv * 32;   // this wave owns m in [mrow0, mrow0+32)

  const float* xb = xg + (size_t)bt * (M_N * DD);

  // prologue: load chunk 0
  f32x8 x0, x1, x2, x3;
  { const float* p = xb + (nq*4)*DD + doct*8;
    x0 = *(const f32x8*)p;        x1 = *(const f32x8*)(p+DD);
    x2 = *(const f32x8*)(p+2*DD); x3 = *(const f32x8*)(p+3*DD); }

  f32x4 acc[2][4];
  #pragma unroll
  for (int ms = 0; ms < 2; ++ms)
    #pragma unroll
    for (int dt = 0; dt < 4; ++dt)
      acc[ms][dt] = f32x4{0.f,0.f,0.f,0.f};

  #pragma unroll
  for (int c = 0; c < 4; ++c) {
    unsigned short* xt = &xT[c & 1][0];
    // transpose-pack chunk c: xT[d][n] = bf16(x[bt][c*KC+n][d])
    #pragma unroll
    for (int e = 0; e < 8; ++e) {
      int d = doct*8 + e;
      unsigned v0 = (unsigned)f2bf(x0[e]) | ((unsigned)f2bf(x1[e]) << 16);
      unsigned v1 = (unsigned)f2bf(x2[e]) | ((unsigned)f2bf(x3[e]) << 16);
      uint2 vv; vv.x = v0; vv.y = v1;
      *(uint2*)(xt + d*XROW + nq*4) = vv;          // ds_write_b64, 2-way (free)
    }
    if (c < 3) {  // async-split: issue next chunk's global loads before barrier
      const float* p = xb + ((c+1)*KC + nq*4)*DD + doct*8;
      x0 = *(const f32x8*)p;        x1 = *(const f32x8*)(p+DD);
      x2 = *(const f32x8*)(p+2*DD); x3 = *(const f32x8*)(p+3*DD);
    }
    __syncthreads();   // 1 barrier per chunk (double-buffered; round-2 pattern)

    #pragma unroll
    for (int kl = 0; kl < 4; ++kl) {
      // A fragments stream straight from global adj (n-contiguous)
      bf16x8 af[2];
      #pragma unroll
      for (int ms = 0; ms < 2; ++ms) {
        const float* ap = adjg + (size_t)(mrow0 + ms*16 + l15) * M_N
                        + c*KC + kl*32 + gg*8;
        f32x8 a = *(const f32x8*)ap;
        u16x8 r;
        #pragma unroll
        for (int i = 0; i < 8; ++i) r[i] = f2bf(a[i]);
        af[ms] = __builtin_bit_cast(bf16x8, r);
      }
      #pragma unroll
      for (int dt = 0; dt < 4; ++dt) {
        bf16x8 bfx = __builtin_bit_cast(bf16x8,
            *(const u16x8*)(xt + (dt*16 + l15)*XROW + kl*32 + gg*8));
        acc[0][dt] = __builtin_amdgcn_mfma_f32_16x16x32_bf16(af[0], bfx, acc[0][dt], 0,0,0);
        acc[1][dt] = __builtin_amdgcn_mfma_f32_16x16x32_bf16(af[1], bfx, acc[1][dt], 0,0,0);
      }
    }
  }

  // epilogue: store H block (bf16) into row-interleaved region of d_out
  #pragma unroll
  for (int ms = 0; ms < 2; ++ms)
    #pragma unroll
    for (int dt = 0; dt < 4; ++dt)
      #pragma unroll
      for (int r = 0; r < 4; ++r) {
        int m = mrow0 + ms*16 + gg*4 + r;          // C row = (lane>>4)*4 + reg
        size_t row = (size_t)bt * M_N + m;
        *(unsigned short*)(hout + row*256 + 2*(dt*16 + l15)) = f2bf(acc[ms][dt][r]);
      }
}

// ---------------- Kernel B ----------------
// out[bt][m][l] = sum_d H[bt][m][d] * W[m][d][l] + bias[m][l]   (f32 result)
// H read as bf16 from the first 128B of each d_out row; full row overwritten.
__global__ __launch_bounds__(256, 4)
void route_mm(const char* __restrict__ hin,    // d_out bytes (H region)
              const float* __restrict__ wgt,   // [512][64][64] f32
              const float* __restrict__ bias,  // [512][64] f32
              float* __restrict__ outg)        // [768][512][64] f32 (same buffer)
{
  __shared__ unsigned short wb[128 * WROW];    // W' for 2 m: [2m][64 l][72]

  const int m0    = blockIdx.x * 2;
  const int btblk = blockIdx.y * 64;
  const int tid   = threadIdx.x;
  const int lane  = tid & 63;
  const int wv    = tid >> 6;
  const int l15   = lane & 15;
  const int gg    = lane >> 4;
  const int dp    = tid & 31;        // d-pair
  const int lo    = tid >> 5;        // l-oct

  // W transpose-pack: W'[mm][l][d] = bf16(W[m0+mm][d][l])
  { const float* q = wgt + ((size_t)m0*64 + dp*2)*64 + lo*8;
    f32x8 w0 = *(const f32x8*)q;          f32x8 w1 = *(const f32x8*)(q+64);
    f32x8 w2 = *(const f32x8*)(q+4096);   f32x8 w3 = *(const f32x8*)(q+4160);
    #pragma unroll
    for (int e = 0; e < 8; ++e) {
      int lrow = lo*8 + e;
      unsigned v0 = (unsigned)f2bf(w0[e]) | ((unsigned)f2bf(w1[e]) << 16);
      unsigned v1 = (unsigned)f2bf(w2[e]) | ((unsigned)f2bf(w3[e]) << 16);
      *(unsigned*)(wb + lrow*WROW + dp*2)        = v0;
      *(unsigned*)(wb + (64 + lrow)*WROW + dp*2) = v1;
    }
  }
  __syncthreads();   // the only barrier in kernel B

  const int btw0 = btblk + wv*16;    // this wave owns bt in [btw0, btw0+16)

  #pragma unroll
  for (int mm = 0; mm < 2; ++mm) {
    const int m = m0 + mm;
    // A fragments: H[bt][m][d], k = d contiguous bf16 -> direct 16B global loads
    bf16x8 afr[2];
    #pragma unroll
    for (int ks = 0; ks < 2; ++ks) {
      const char* hp = hin + ((size_t)(btw0 + l15)*M_N + m)*256 + ks*64 + gg*16;
      afr[ks] = __builtin_bit_cast(bf16x8, *(const u16x8*)hp);
    }
    f32x4 acc[4];
    #pragma unroll
    for (int lt = 0; lt < 4; ++lt) acc[lt] = f32x4{0.f,0.f,0.f,0.f};
    #pragma unroll
    for (int lt = 0; lt < 4; ++lt)
      #pragma unroll
      for (int ks = 0; ks < 2; ++ks) {
        bf16x8 bfr = __builtin_bit_cast(bf16x8,
            *(const u16x8*)(wb + (mm*64 + lt*16 + l15)*WROW + ks*32 + gg*8));
        acc[lt] = __builtin_amdgcn_mfma_f32_16x16x32_bf16(afr[ks], bfr, acc[lt], 0,0,0);
      }
    // bias + store (stores data-depend on the H loads via MFMA -> ordered;
    // each wave reads/writes only its own 16 bt rows for this m)
    #pragma unroll
    for (int lt = 0; lt < 4; ++lt) {
      float bv = bias[m*64 + lt*16 + l15];
      #pragma unroll
      for (int r = 0; r < 4; ++r) {
        size_t row = (size_t)(btw0 + gg*4 + r)*M_N + m;
        outg[row*64 + lt*16 + l15] = acc[lt][r] + bv;
      }
    }
  }
}

extern "C" void kernel_launch(void* const* d_in, const int* in_sizes, int n_in,
                              void* d_out, int out_size, void* d_ws, size_t ws_size,
                              hipStream_t stream) {
  const float* xg   = (const float*)d_in[0];
  const float* adjg = (const float*)d_in[1];
  const float* wgt  = (const float*)d_in[2];
  const float* bg   = (const float*)d_in[3];

  gconv_h<<<dim3(BT_TOT, 4), dim3(256), 0, stream>>>(xg, adjg, (char*)d_out);
  route_mm<<<dim3(M_N/2, BT_TOT/64), dim3(256), 0, stream>>>(
      (const char*)d_out, wgt, bg, (float*)d_out);
}

// Round 4
// 105.643 us; speedup vs baseline: 3.2112x; 1.6128x over previous
//
#include <hip/hip_runtime.h>
#include <stdint.h>

typedef short bf16x8 __attribute__((ext_vector_type(8)));
typedef unsigned short u16x8 __attribute__((ext_vector_type(8)));
typedef float f32x4 __attribute__((ext_vector_type(4)));
typedef float f32x8 __attribute__((ext_vector_type(8)));

constexpr int BT_TOT = 768;   // B*T
constexpr int M_N    = 512;   // nodes (contraction length for stage 1)
constexpr int DD     = 64;    // Din = Dout
constexpr int WROW   = 72;    // W' row stride in route_mm (144B, bank step 4)

__device__ __forceinline__ unsigned short f2bf(float f) {
  unsigned u = __builtin_bit_cast(unsigned, f);
  u += 0x7fffu + ((u >> 16) & 1u);          // RNE
  return (unsigned short)(u >> 16);
}

// ---------------- prep: adj f32 -> bf16 (once) ----------------
__global__ __launch_bounds__(256)
void prep_adj(const float* __restrict__ adjg, unsigned short* __restrict__ wsadj) {
  int i = (blockIdx.x * 256 + threadIdx.x) * 8;   // 512*512 elems, 8 per thread
  f32x8 a = *(const f32x8*)(adjg + i);
  u16x8 r;
  #pragma unroll
  for (int j = 0; j < 8; ++j) r[j] = f2bf(a[j]);
  *(u16x8*)(wsadj + i) = r;
}

// ---------------- Kernel A ----------------
// H[bt][m][d] = sum_n adj[m][n] * x[bt][n][d]  (bf16), one WG per bt, all 512 m.
// H goes into the FIRST 128B of each 256B d_out row (row = bt*512+m); kernel B
// overwrites each full row afterwards (stream-ordered), so d_out is the scratch.
// xT in LDS is XOR-swizzled: elem(d, n) at d*512 + ((n/8)^(d&7))*8 + n%8.
template<bool WS>
__global__ __launch_bounds__(256, 2)
void gconv_h(const float* __restrict__ xg,             // [768][512][64] f32
             const float* __restrict__ adjf,           // [512][512] f32 (fallback)
             const unsigned short* __restrict__ adjb,  // [512][512] bf16 (ws path)
             char* __restrict__ hout)
{
  __shared__ unsigned short xT[64 * 512];   // 65536 B -> 2 WG/CU

  const int bt   = blockIdx.x;
  const int tid  = threadIdx.x;
  const int lane = tid & 63;
  const int wv   = tid >> 6;        // wave 0..3: owns m in [wv*128, wv*128+128)
  const int l15  = lane & 15;
  const int gg   = lane >> 4;       // k-group 0..3
  const int nq   = tid & 31;        // n-quad for staging
  const int doct = tid >> 5;        // d-oct for staging

  const float* xb = xg + (size_t)bt * (M_N * DD);

  // ---- stage ALL of x[bt] transposed+swizzled into LDS; ONE barrier total ----
  f32x8 x0, x1, x2, x3;
  { const float* p = xb + (nq*4)*DD + doct*8;
    x0 = *(const f32x8*)p;        x1 = *(const f32x8*)(p+DD);
    x2 = *(const f32x8*)(p+2*DD); x3 = *(const f32x8*)(p+3*DD); }
  #pragma unroll
  for (int c = 0; c < 4; ++c) {
    #pragma unroll
    for (int e = 0; e < 8; ++e) {
      int d = doct*8 + e;
      unsigned v0 = (unsigned)f2bf(x0[e]) | ((unsigned)f2bf(x1[e]) << 16);
      unsigned v1 = (unsigned)f2bf(x2[e]) | ((unsigned)f2bf(x3[e]) << 16);
      uint2 vv; vv.x = v0; vv.y = v1;
      // n = c*128 + nq*4: granule j = c*16 + nq/2 (swizzled), intra = (nq&1)*4 elems
      *(uint2*)(&xT[d*512 + (((c*16) + (nq>>1)) ^ e)*8 + (nq&1)*4]) = vv;
    }
    if (c < 3) {
      const float* p = xb + ((c+1)*128 + nq*4)*DD + doct*8;
      x0 = *(const f32x8*)p;        x1 = *(const f32x8*)(p+DD);
      x2 = *(const f32x8*)(p+2*DD); x3 = *(const f32x8*)(p+3*DD);
    }
  }
  __syncthreads();   // the only barrier in kernel A

  // ---- register-resident GEMM: acc[8 m-tiles][4 d-tiles], B reused 8x ----
  f32x4 acc[8][4];
  #pragma unroll
  for (int mt = 0; mt < 8; ++mt)
    #pragma unroll
    for (int dt = 0; dt < 4; ++dt) acc[mt][dt] = f32x4{0.f,0.f,0.f,0.f};

  #pragma unroll 2
  for (int kl = 0; kl < 16; ++kl) {
    bf16x8 afr[8];
    #pragma unroll
    for (int mt = 0; mt < 8; ++mt) {
      const int m = wv*128 + mt*16 + l15;
      if (WS) {
        afr[mt] = __builtin_bit_cast(bf16x8,
            *(const u16x8*)(adjb + (size_t)m*M_N + kl*32 + gg*8));
      } else {
        f32x8 a = *(const f32x8*)(adjf + (size_t)m*M_N + kl*32 + gg*8);
        u16x8 r;
        #pragma unroll
        for (int j = 0; j < 8; ++j) r[j] = f2bf(a[j]);
        afr[mt] = __builtin_bit_cast(bf16x8, r);
      }
    }
    #pragma unroll
    for (int dt = 0; dt < 4; ++dt) {
      const int d = dt*16 + l15;
      bf16x8 bfx = __builtin_bit_cast(bf16x8,
          *(const u16x8*)(&xT[d*512 + ((kl*4 + gg) ^ (l15 & 7))*8]));
      #pragma unroll
      for (int mt = 0; mt < 8; ++mt)
        acc[mt][dt] = __builtin_amdgcn_mfma_f32_16x16x32_bf16(afr[mt], bfx,
                                                              acc[mt][dt], 0,0,0);
    }
  }

  // ---- epilogue: H store (bf16, low half of each d_out row) ----
  #pragma unroll
  for (int mt = 0; mt < 8; ++mt)
    #pragma unroll
    for (int dt = 0; dt < 4; ++dt)
      #pragma unroll
      for (int r = 0; r < 4; ++r) {
        int m = wv*128 + mt*16 + gg*4 + r;     // C row = (lane>>4)*4 + reg
        int d = dt*16 + l15;
        *(unsigned short*)(hout + ((size_t)bt*M_N + m)*256 + 2*d)
            = f2bf(acc[mt][dt][r]);
      }
}

// ---------------- Kernel B (unchanged from round 3, verified) ----------------
__global__ __launch_bounds__(256, 4)
void route_mm(const char* __restrict__ hin,
              const float* __restrict__ wgt,
              const float* __restrict__ bias,
              float* __restrict__ outg)
{
  __shared__ unsigned short wb[128 * WROW];

  const int m0    = blockIdx.x * 2;
  const int btblk = blockIdx.y * 64;
  const int tid   = threadIdx.x;
  const int lane  = tid & 63;
  const int wv    = tid >> 6;
  const int l15   = lane & 15;
  const int gg    = lane >> 4;
  const int dp    = tid & 31;
  const int lo    = tid >> 5;

  { const float* q = wgt + ((size_t)m0*64 + dp*2)*64 + lo*8;
    f32x8 w0 = *(const f32x8*)q;          f32x8 w1 = *(const f32x8*)(q+64);
    f32x8 w2 = *(const f32x8*)(q+4096);   f32x8 w3 = *(const f32x8*)(q+4160);
    #pragma unroll
    for (int e = 0; e < 8; ++e) {
      int lrow = lo*8 + e;
      unsigned v0 = (unsigned)f2bf(w0[e]) | ((unsigned)f2bf(w1[e]) << 16);
      unsigned v1 = (unsigned)f2bf(w2[e]) | ((unsigned)f2bf(w3[e]) << 16);
      *(unsigned*)(wb + lrow*WROW + dp*2)        = v0;
      *(unsigned*)(wb + (64 + lrow)*WROW + dp*2) = v1;
    }
  }
  __syncthreads();

  const int btw0 = btblk + wv*16;

  #pragma unroll
  for (int mm = 0; mm < 2; ++mm) {
    const int m = m0 + mm;
    bf16x8 afr[2];
    #pragma unroll
    for (int ks = 0; ks < 2; ++ks) {
      const char* hp = hin + ((size_t)(btw0 + l15)*M_N + m)*256 + ks*64 + gg*16;
      afr[ks] = __builtin_bit_cast(bf16x8, *(const u16x8*)hp);
    }
    f32x4 acc[4];
    #pragma unroll
    for (int lt = 0; lt < 4; ++lt) acc[lt] = f32x4{0.f,0.f,0.f,0.f};
    #pragma unroll
    for (int lt = 0; lt < 4; ++lt)
      #pragma unroll
      for (int ks = 0; ks < 2; ++ks) {
        bf16x8 bfr = __builtin_bit_cast(bf16x8,
            *(const u16x8*)(wb + (mm*64 + lt*16 + l15)*WROW + ks*32 + gg*8));
        acc[lt] = __builtin_amdgcn_mfma_f32_16x16x32_bf16(afr[ks], bfr, acc[lt], 0,0,0);
      }
    #pragma unroll
    for (int lt = 0; lt < 4; ++lt) {
      float bv = bias[m*64 + lt*16 + l15];
      #pragma unroll
      for (int r = 0; r < 4; ++r) {
        size_t row = (size_t)(btw0 + gg*4 + r)*M_N + m;
        outg[row*64 + lt*16 + l15] = acc[lt][r] + bv;
      }
    }
  }
}

extern "C" void kernel_launch(void* const* d_in, const int* in_sizes, int n_in,
                              void* d_out, int out_size, void* d_ws, size_t ws_size,
                              hipStream_t stream) {
  const float* xg   = (const float*)d_in[0];
  const float* adjg = (const float*)d_in[1];
  const float* wgt  = (const float*)d_in[2];
  const float* bg   = (const float*)d_in[3];

  const size_t adj_bf_bytes = (size_t)M_N * M_N * 2;   // 512 KB
  if (ws_size >= adj_bf_bytes) {
    unsigned short* wsadj = (unsigned short*)d_ws;
    prep_adj<<<dim3(M_N * M_N / (256 * 8)), dim3(256), 0, stream>>>(adjg, wsadj);
    gconv_h<true><<<dim3(BT_TOT), dim3(256), 0, stream>>>(
        xg, adjg, wsadj, (char*)d_out);
  } else {
    gconv_h<false><<<dim3(BT_TOT), dim3(256), 0, stream>>>(
        xg, adjg, nullptr, (char*)d_out);
  }
  route_mm<<<dim3(M_N/2, BT_TOT/64), dim3(256), 0, stream>>>(
      (const char*)d_out, wgt, bg, (float*)d_out);
}